// Round 4
// baseline (392.734 us; speedup 1.0000x reference)
//
#include <hip/hip_runtime.h>

#define M 64
#define FG_T 0.6f
#define BG_T 0.4f
// packed column entry: (iou_bits << 32) | ~n  — iou in (0,2] so bit pattern is
// monotone; ties in iou resolve to SMALLER n (first occurrence, matches np argmax).
// 0 = "no entry" (any real entry has iou_bits > 0, so packed > 0); ws is
// memset to 0 each launch. fixup decodes p==0 -> anchor 0 (np argmax of an
// all-zero column), which also guards the (practically impossible) no-overlap GT.

__global__ __launch_bounds__(256) void encode_kernel(
    const float* __restrict__ gt,    // [B, M, 4] xyxy
    const int*   __restrict__ lab,   // [B, M]
    const float* __restrict__ db,    // [N, 4] xywh (cx, cy, w, h)
    float* __restrict__ out_loc,     // [B, N, 4]
    float* __restrict__ out_cls,     // [B, N] (written as float)
    unsigned long long* __restrict__ col, // [B, M] packed column max (0-initialized)
    int N)
{
#pragma clang fp contract(off)
    __shared__ float s_area[M];
    __shared__ unsigned int s_colmax[M];  // running column max, float bits (monotone)
    __shared__ unsigned long long s_col[M];

    const int b   = blockIdx.y;
    const int tid = threadIdx.x;
    const float4* __restrict__ gtb = (const float4*)gt + b * M;  // block-uniform

    if (tid < M) {
        float4 g = gtb[tid];
        s_area[tid]   = (g.z - g.x) * (g.w - g.y);   // same op order as reference
        s_colmax[tid] = 0u;
        s_col[tid]    = 0ull;
    }
    __syncthreads();

    const int  n     = blockIdx.x * 256 + tid;
    const bool valid = (n < N);
    const int  nl    = valid ? n : (N - 1);

    const float4 d = ((const float4*)db)[nl];
    // db_xyxy exactly as reference: c - wh/2, c + wh/2 (div by 2 is exact)
    const float ax0 = d.x - d.z / 2.0f;
    const float ay0 = d.y - d.w / 2.0f;
    const float ax1 = d.x + d.z / 2.0f;
    const float ay1 = d.y + d.w / 2.0f;
    const float area_a = (ax1 - ax0) * (ay1 - ay0);  // from xyxy, as reference

    // best=0, bi=0: a row whose ious are all exactly 0 keeps bi=0, which is
    // np.argmax(first-max) semantics; strict > gives first-occurrence otherwise.
    float best = 0.0f;
    int   bi   = 0;

    float4 gnext = gtb[0];   // software-pipelined block-uniform scalar load
    for (int m = 0; m < M; ++m) {
        float4 g = gnext;
        gnext = gtb[(m + 1) & (M - 1)];   // uniform, branch-free prefetch

        float ltx = fmaxf(ax0, g.x);
        float lty = fmaxf(ay0, g.y);
        float rbx = fminf(ax1, g.z);
        float rby = fminf(ay1, g.w);
        float w = fmaxf(rbx - ltx, 0.0f);
        float h = fmaxf(rby - lty, 0.0f);
        float inter = w * h;

        // Wave-uniform skip when no lane intersects GT m. Inside the branch,
        // lanes with inter==0 get iou = 0/denom = +0.0 — bit-identical to the
        // branchless version, so argmax/threshold ordering is unaffected.
        if (__any(inter > 0.0f)) {
            // colmax read issued before the div so its LDS latency hides under it
            unsigned int cm = s_colmax[m];
            float iou = inter / ((area_a + s_area[m]) - inter);  // IEEE div: bit-exact vs np

            if (iou > best) { best = iou; bi = m; }

            // Record-breaking lanes (rare after warm-up) update the column max
            // directly via DS atomics — no wave reduction, no swizzle chains.
            // >= (not >) so an equal-iou smaller-n lane can still win the
            // packed tie-break. Stale cm reads are benign (monotone).
            if (valid && (iou > 0.0f) && (__float_as_uint(iou) >= cm)) {
                unsigned long long p =
                    (((unsigned long long)__float_as_uint(iou)) << 32)
                    | (unsigned int)(~(unsigned int)n);
                atomicMax(&s_col[m], p);
                atomicMax(&s_colmax[m], __float_as_uint(iou));
            }
        }
    }
    __syncthreads();

    if (tid < M) {
        unsigned long long p = s_col[tid];
        if (p != 0ull) atomicMax(&col[b * M + tid], p);
    }

    if (valid) {
        float t = best;
        float cv;
        if (t < BG_T)      cv = 0.0f;
        else if (t < FG_T) cv = -1.0f;
        else               cv = (float)(lab[b * M + bi] + 1);

        float4 g = gtb[bi];
        float bcx = (g.x + g.z) / 2.0f;
        float bcy = (g.y + g.w) / 2.0f;
        float bw  = g.z - g.x;
        float bh  = g.w - g.y;
        float lx = ((bcx - d.x) / d.z) / 0.1f;
        float ly = ((bcy - d.y) / d.w) / 0.1f;
        float lw = __logf(bw / d.z) / 0.2f;   // ~1e-6 abs err vs 3.54 threshold
        float lh = __logf(bh / d.w) / 0.2f;

        ((float4*)out_loc)[(size_t)b * N + n] = make_float4(lx, ly, lw, lh);
        out_cls[(size_t)b * N + n] = cv;
    }
}

// Apply the best_p_idx override: best_t_idx[best_p[m]] = m (last write wins),
// best_t -> 2.0 so cls = lab+1 and loc re-encoded from gt[m].
__global__ void fixup_kernel(
    const float* __restrict__ gt,
    const int*   __restrict__ lab,
    const float* __restrict__ db,
    const unsigned long long* __restrict__ col,
    float* __restrict__ out_loc,
    float* __restrict__ out_cls,
    int N)
{
#pragma clang fp contract(off)
    __shared__ int s_a[M];
    const int b = blockIdx.x;
    const int m = threadIdx.x;  // 64 threads

    unsigned long long p = col[b * M + m];
    // p==0: no anchor overlapped GT m (practically impossible) -> np argmax
    // of an all-zero column = 0.
    int a = (p == 0ull) ? 0 : (int)(~(unsigned int)(p & 0xFFFFFFFFull));
    s_a[m] = a;
    __syncthreads();

    // last-write-wins for duplicate anchors (np fancy assignment semantics)
    bool write = true;
    for (int mm = m + 1; mm < M; ++mm) {
        if (s_a[mm] == a) { write = false; break; }
    }
    if (write) {
        float4 d = ((const float4*)db)[a];
        float4 g = ((const float4*)gt)[b * M + m];
        float bcx = (g.x + g.z) / 2.0f;
        float bcy = (g.y + g.w) / 2.0f;
        float bw  = g.z - g.x;
        float bh  = g.w - g.y;
        float lx = ((bcx - d.x) / d.z) / 0.1f;
        float ly = ((bcy - d.y) / d.w) / 0.1f;
        float lw = __logf(bw / d.z) / 0.2f;
        float lh = __logf(bh / d.w) / 0.2f;

        ((float4*)out_loc)[(size_t)b * N + a] = make_float4(lx, ly, lw, lh);
        out_cls[(size_t)b * N + a] = (float)(lab[b * M + m] + 1);  // best_t = 2.0 >= FG_T
    }
}

extern "C" void kernel_launch(void* const* d_in, const int* in_sizes, int n_in,
                              void* d_out, int out_size, void* d_ws, size_t ws_size,
                              hipStream_t stream) {
    const float* gt  = (const float*)d_in[0];   // gt_boxes  [B, M, 4] xyxy
    const int*   lab = (const int*)d_in[1];     // labels    [B, M]
    const float* db  = (const float*)d_in[2];   // default_boxes [N, 4] xywh

    const int B = in_sizes[1] / M;
    const int N = in_sizes[2] / 4;

    float* out_loc = (float*)d_out;                       // [B, N, 4]
    float* out_cls = out_loc + (size_t)B * N * 4;         // [B, N]

    unsigned long long* col = (unsigned long long*)d_ws;  // [B, M] — 16 KB

    // 0 is the identity for the packed max (all real entries > 0) — a memset
    // node replaces the init kernel.
    hipMemsetAsync(col, 0, (size_t)B * M * sizeof(unsigned long long), stream);
    encode_kernel<<<dim3((N + 255) / 256, B), dim3(256), 0, stream>>>(
        gt, lab, db, out_loc, out_cls, col, N);
    fixup_kernel<<<dim3(B), dim3(M), 0, stream>>>(gt, lab, db, col, out_loc, out_cls, N);
}

// Round 5
// 203.659 us; speedup vs baseline: 1.9284x; 1.9284x over previous
//
#include <hip/hip_runtime.h>

#define M 64
#define FG_T 0.6f
#define BG_T 0.4f
#define CHUNK 512          // anchors per col_kernel block
#define PER_T (CHUNK / 4)  // anchors per thread (4 q-groups of 64 GT-threads)

// packed column entry: (iou_bits << 32) | ~n — iou in (0,1] so the bit pattern
// is monotone; ties in iou resolve to SMALLER n (first occurrence = np argmax).
// 0 = "no entry"; ws is memset to 0 each launch. fixup decodes p==0 -> anchor 0
// (np argmax of an all-zero column).

__device__ inline float readlane_f(float v, int lane) {
    return __uint_as_float(__builtin_amdgcn_readlane(__float_as_uint(v), (unsigned)lane));
}

// ---------------- row kernel: per-anchor best GT (pure per-lane) ----------------
__global__ __launch_bounds__(256) void row_kernel(
    const float* __restrict__ gt,    // [B, M, 4] xyxy
    const int*   __restrict__ lab,   // [B, M]
    const float* __restrict__ db,    // [N, 4] xywh
    float* __restrict__ out_loc,     // [B, N, 4]
    float* __restrict__ out_cls,     // [B, N]
    int N)
{
#pragma clang fp contract(off)
    const int b   = blockIdx.y;
    const int tid = threadIdx.x;
    const float4* __restrict__ gtb = (const float4*)gt + b * M;

    const int  n     = blockIdx.x * 256 + tid;
    const bool valid = (n < N);
    const int  nl    = valid ? n : (N - 1);

    const float4 d = ((const float4*)db)[nl];
    // db_xyxy exactly as reference: c - wh/2, c + wh/2 (div by 2 is exact)
    const float ax0 = d.x - d.z / 2.0f;
    const float ay0 = d.y - d.w / 2.0f;
    const float ax1 = d.x + d.z / 2.0f;
    const float ay1 = d.y + d.w / 2.0f;
    const float area_a = (ax1 - ax0) * (ay1 - ay0);

    // one-time wave bbox (union of the wave's 64 anchors)
    float wx0 = ax0, wy0 = ay0, wx1 = ax1, wy1 = ay1;
    #pragma unroll
    for (int off = 1; off < 64; off <<= 1) {
        wx0 = fminf(wx0, __shfl_xor(wx0, off));
        wy0 = fminf(wy0, __shfl_xor(wy0, off));
        wx1 = fmaxf(wx1, __shfl_xor(wx1, off));
        wy1 = fmaxf(wy1, __shfl_xor(wy1, off));
    }

    // lane l caches GT l in registers; candidate iff GT strictly overlaps wave bbox.
    // (touch-only => inter==0 => iou==0 => can never beat best=0, safe to skip)
    const int    l  = tid & 63;
    const float4 gl = gtb[l];
    const float  area_l = (gl.z - gl.x) * (gl.w - gl.y);  // reference op order
    const bool cand = (gl.x < wx1) && (gl.z > wx0) && (gl.y < wy1) && (gl.w > wy0);
    unsigned long long mask = __ballot((int)cand);

    // best=0, bi=0: all-zero row keeps bi=0 (np argmax); strict > = first max.
    float best = 0.0f;
    int   bi   = 0;

    while (mask) {
        const int m = __builtin_amdgcn_readfirstlane(__builtin_ctzll(mask));
        mask &= mask - 1;
        // GT m fragments pulled from lane m's registers (v_readlane -> SGPR)
        const float gx0 = readlane_f(gl.x, m);
        const float gy0 = readlane_f(gl.y, m);
        const float gx1 = readlane_f(gl.z, m);
        const float gy1 = readlane_f(gl.w, m);
        const float ab  = readlane_f(area_l, m);

        float ltx = fmaxf(ax0, gx0);
        float lty = fmaxf(ay0, gy0);
        float rbx = fminf(ax1, gx1);
        float rby = fminf(ay1, gy1);
        float w = fmaxf(rbx - ltx, 0.0f);
        float h = fmaxf(rby - lty, 0.0f);
        float inter = w * h;

        if (__any(inter > 0.0f)) {
            float iou = inter / ((area_a + ab) - inter);  // IEEE div: bit-exact vs np
            if (iou > best) { best = iou; bi = m; }
        }
    }

    if (valid) {
        float cv;
        if (best < BG_T)      cv = 0.0f;
        else if (best < FG_T) cv = -1.0f;
        else                  cv = (float)(lab[b * M + bi] + 1);

        float4 g = gtb[bi];   // divergent gather, tiny table, L1-resident
        float bcx = (g.x + g.z) / 2.0f;
        float bcy = (g.y + g.w) / 2.0f;
        float bw  = g.z - g.x;
        float bh  = g.w - g.y;
        float lx = ((bcx - d.x) / d.z) / 0.1f;
        float ly = ((bcy - d.y) / d.w) / 0.1f;
        float lw = __logf(bw / d.z) / 0.2f;   // ~1e-6 abs err vs 3.54 threshold
        float lh = __logf(bh / d.w) / 0.2f;

        ((float4*)out_loc)[(size_t)b * N + n] = make_float4(lx, ly, lw, lh);
        out_cls[(size_t)b * N + n] = cv;
    }
}

// ---------------- col kernel: per-GT best anchor (transposed, per-lane) ----------------
// 256 threads = 4 anchor-subranges (q) x 64 GTs (m). Thread (q,m) scans PER_T
// anchors serially with GT m register-resident; column state is thread-local.
__global__ __launch_bounds__(256) void col_kernel(
    const float* __restrict__ gt,    // [B, M, 4] xyxy
    const float* __restrict__ db,    // [N, 4] xywh
    unsigned long long* __restrict__ col, // [B, M] packed, 0-initialized
    int N)
{
#pragma clang fp contract(off)
    __shared__ unsigned long long s_col[M];
    const int b = blockIdx.y;
    const int q = threadIdx.x >> 6;
    const int m = threadIdx.x & 63;
    if (threadIdx.x < M) s_col[threadIdx.x] = 0ull;
    __syncthreads();

    const float4 g = ((const float4*)gt)[b * M + m];
    const float  area_g = (g.z - g.x) * (g.w - g.y);
    // provable upper bound on 1/area_g: iou = inter/union <= inter/area_g
    const float  inv_up = (1.0f / area_g) * 1.000002f;

    float best = 0.0f;
    int   bn   = 0;

    const int base = blockIdx.x * CHUNK + q * PER_T;
    for (int i = 0; i < PER_T; ++i) {
        const int n = base + i;          // wave-uniform
        if (n >= N) break;               // wave-uniform exit
        const int ns = __builtin_amdgcn_readfirstlane(n);
        const float4 d = ((const float4*)db)[ns];   // scalar (broadcast) load

        const float ax0 = d.x - d.z / 2.0f;
        const float ay0 = d.y - d.w / 2.0f;
        const float ax1 = d.x + d.z / 2.0f;
        const float ay1 = d.y + d.w / 2.0f;

        float ltx = fmaxf(ax0, g.x);
        float lty = fmaxf(ay0, g.y);
        float rbx = fminf(ax1, g.z);
        float rby = fminf(ay1, g.w);
        float w = fmaxf(rbx - ltx, 0.0f);
        float h = fmaxf(rby - lty, 0.0f);
        float inter = w * h;

        // skip the IEEE div unless some lane could beat its running best:
        // bound = inter*inv_up >= inter/area_g >= iou  (rounded safely upward)
        if (__any(inter * inv_up > best)) {
            float area_a = (ax1 - ax0) * (ay1 - ay0);
            float iou = inter / ((area_a + area_g) - inter);  // bit-exact vs np
            // strict > + ascending n = np first-occurrence argmax; inter==0
            // lanes get iou=+0.0 which never passes.
            if (iou > best) { best = iou; bn = n; }
        }
    }

    if (best > 0.0f) {
        unsigned long long p =
            (((unsigned long long)__float_as_uint(best)) << 32)
            | (unsigned int)(~(unsigned int)bn);
        atomicMax(&s_col[m], p);    // 4 threads per address
    }
    __syncthreads();
    if (threadIdx.x < M) {
        unsigned long long p = s_col[threadIdx.x];
        if (p != 0ull) atomicMax(&col[b * M + threadIdx.x], p);
    }
}

// Apply the best_p_idx override: best_t_idx[best_p[m]] = m (last write wins),
// best_t -> 2.0 so cls = lab+1 and loc re-encoded from gt[m].
__global__ void fixup_kernel(
    const float* __restrict__ gt,
    const int*   __restrict__ lab,
    const float* __restrict__ db,
    const unsigned long long* __restrict__ col,
    float* __restrict__ out_loc,
    float* __restrict__ out_cls,
    int N)
{
#pragma clang fp contract(off)
    __shared__ int s_a[M];
    const int b = blockIdx.x;
    const int m = threadIdx.x;  // 64 threads

    unsigned long long p = col[b * M + m];
    // p==0: no anchor overlapped GT m -> np argmax of all-zero column = 0.
    int a = (p == 0ull) ? 0 : (int)(~(unsigned int)(p & 0xFFFFFFFFull));
    s_a[m] = a;
    __syncthreads();

    // last-write-wins for duplicate anchors (np fancy assignment semantics)
    bool write = true;
    for (int mm = m + 1; mm < M; ++mm) {
        if (s_a[mm] == a) { write = false; break; }
    }
    if (write) {
        float4 d = ((const float4*)db)[a];
        float4 g = ((const float4*)gt)[b * M + m];
        float bcx = (g.x + g.z) / 2.0f;
        float bcy = (g.y + g.w) / 2.0f;
        float bw  = g.z - g.x;
        float bh  = g.w - g.y;
        float lx = ((bcx - d.x) / d.z) / 0.1f;
        float ly = ((bcy - d.y) / d.w) / 0.1f;
        float lw = __logf(bw / d.z) / 0.2f;
        float lh = __logf(bh / d.w) / 0.2f;

        ((float4*)out_loc)[(size_t)b * N + a] = make_float4(lx, ly, lw, lh);
        out_cls[(size_t)b * N + a] = (float)(lab[b * M + m] + 1);  // best_t = 2.0
    }
}

extern "C" void kernel_launch(void* const* d_in, const int* in_sizes, int n_in,
                              void* d_out, int out_size, void* d_ws, size_t ws_size,
                              hipStream_t stream) {
    const float* gt  = (const float*)d_in[0];   // gt_boxes  [B, M, 4] xyxy
    const int*   lab = (const int*)d_in[1];     // labels    [B, M]
    const float* db  = (const float*)d_in[2];   // default_boxes [N, 4] xywh

    const int B = in_sizes[1] / M;
    const int N = in_sizes[2] / 4;

    float* out_loc = (float*)d_out;                       // [B, N, 4]
    float* out_cls = out_loc + (size_t)B * N * 4;         // [B, N]

    unsigned long long* col = (unsigned long long*)d_ws;  // [B, M] — 16 KB

    hipMemsetAsync(col, 0, (size_t)B * M * sizeof(unsigned long long), stream);
    row_kernel<<<dim3((N + 255) / 256, B), dim3(256), 0, stream>>>(
        gt, lab, db, out_loc, out_cls, N);
    col_kernel<<<dim3((N + CHUNK - 1) / CHUNK, B), dim3(256), 0, stream>>>(
        gt, db, col, N);
    fixup_kernel<<<dim3(B), dim3(M), 0, stream>>>(gt, lab, db, col, out_loc, out_cls, N);
}

// Round 6
// 132.279 us; speedup vs baseline: 2.9690x; 1.5396x over previous
//
#include <hip/hip_runtime.h>

#define M 64
#define FG_T 0.6f
#define BG_T 0.4f

// packed column entry: (iou_bits << 32) | ~n — iou in (0,1] so the bit pattern
// is monotone; ties in iou resolve to SMALLER n (first occurrence = np argmax).
// 0 = "no entry" (lb > 0 always for this data, so every GT gets a real entry;
// fixup still guards p==0 -> anchor 0 = np argmax of an all-zero column).

__device__ inline float readlane_f(float v, int lane) {
    return __uint_as_float(__builtin_amdgcn_readlane(__float_as_uint(v), (unsigned)lane));
}

// -------- lb kernel: per-(b,m) lower bound on the column max + col zero-init ------
// For GT m, evaluate the EXACT iou (same op order as everywhere) of the 54 db
// anchors at the grid cell nearest the GT center (6 levels x 9 shapes). Each is
// a real anchor's iou -> max over them is a guaranteed lower bound on the
// column max. In practice the nearest-center anchor usually IS the argmax.
__global__ __launch_bounds__(64) void lb_kernel(
    const float* __restrict__ gt,    // [B, M, 4] xyxy
    const float* __restrict__ db,    // [N, 4] xywh
    float* __restrict__ lb,          // [B, M]
    unsigned long long* __restrict__ col)  // [B, M] — zero-initialized here
{
#pragma clang fp contract(off)
    const int b = blockIdx.x;
    const int m = threadIdx.x;

    col[b * M + m] = 0ull;

    const float4 g = ((const float4*)gt)[b * M + m];
    const float area_g = (g.z - g.x) * (g.w - g.y);   // reference op order
    const float gcx = (g.x + g.z) * 0.5f;
    const float gcy = (g.y + g.w) * 0.5f;

    const int   fms[6]  = {64, 32, 16, 8, 4, 2};
    const float stp[6]  = {8.0f, 16.0f, 32.0f, 64.0f, 128.0f, 256.0f};
    const int   off[6]  = {0, 36864, 46080, 48384, 48960, 49104};

    float best = 0.0f;
    #pragma unroll
    for (int i = 0; i < 6; ++i) {
        int fx = fms[i];
        int x = (int)(gcx / stp[i]); x = min(max(x, 0), fx - 1);
        int y = (int)(gcy / stp[i]); y = min(max(y, 0), fx - 1);
        int base = off[i] + (y * fx + x) * 9;
        for (int a = 0; a < 9; ++a) {
            float4 d = ((const float4*)db)[base + a];
            float ax0 = d.x - d.z / 2.0f;
            float ay0 = d.y - d.w / 2.0f;
            float ax1 = d.x + d.z / 2.0f;
            float ay1 = d.y + d.w / 2.0f;
            float area_a = (ax1 - ax0) * (ay1 - ay0);
            float ltx = fmaxf(ax0, g.x);
            float lty = fmaxf(ay0, g.y);
            float rbx = fminf(ax1, g.z);
            float rby = fminf(ay1, g.w);
            float w = fmaxf(rbx - ltx, 0.0f);
            float h = fmaxf(rby - lty, 0.0f);
            float inter = w * h;
            float iou = inter / ((area_a + area_g) - inter);  // exact anchor iou
            best = fmaxf(best, iou);
        }
    }
    lb[b * M + m] = best;
}

// ---------------- row kernel: per-anchor best GT + column candidates ----------------
__global__ __launch_bounds__(256) void row_kernel(
    const float* __restrict__ gt,    // [B, M, 4] xyxy
    const int*   __restrict__ lab,   // [B, M]
    const float* __restrict__ db,    // [N, 4] xywh
    const float* __restrict__ lb,    // [B, M] column-max lower bound
    float* __restrict__ out_loc,     // [B, N, 4]
    float* __restrict__ out_cls,     // [B, N]
    unsigned long long* __restrict__ col,  // [B, M] packed column max
    int N)
{
#pragma clang fp contract(off)
    const int b   = blockIdx.y;
    const int tid = threadIdx.x;
    const float4* __restrict__ gtb = (const float4*)gt + b * M;

    const int  n     = blockIdx.x * 256 + tid;
    const bool valid = (n < N);
    const int  nl    = valid ? n : (N - 1);

    const float4 d = ((const float4*)db)[nl];
    // db_xyxy exactly as reference: c - wh/2, c + wh/2 (div by 2 is exact)
    const float ax0 = d.x - d.z / 2.0f;
    const float ay0 = d.y - d.w / 2.0f;
    const float ax1 = d.x + d.z / 2.0f;
    const float ay1 = d.y + d.w / 2.0f;
    const float area_a = (ax1 - ax0) * (ay1 - ay0);

    // one-time wave bbox (union of the wave's 64 anchors)
    float wx0 = ax0, wy0 = ay0, wx1 = ax1, wy1 = ay1;
    #pragma unroll
    for (int off = 1; off < 64; off <<= 1) {
        wx0 = fminf(wx0, __shfl_xor(wx0, off));
        wy0 = fminf(wy0, __shfl_xor(wy0, off));
        wx1 = fmaxf(wx1, __shfl_xor(wx1, off));
        wy1 = fmaxf(wy1, __shfl_xor(wy1, off));
    }

    // lane l caches GT l (and its lb) in registers; candidate iff GT strictly
    // overlaps the wave bbox (touch-only => inter==0 => iou==0, safe to skip:
    // neither row-best nor column candidate since lb > 0).
    const int    l  = tid & 63;
    const float4 gl = gtb[l];
    const float  area_l = (gl.z - gl.x) * (gl.w - gl.y);  // reference op order
    const float  lbl    = lb[b * M + l];
    const bool cand = (gl.x < wx1) && (gl.z > wx0) && (gl.y < wy1) && (gl.w > wy0);
    unsigned long long mask = __ballot((int)cand);

    // best=0, bi=0: all-zero row keeps bi=0 (np argmax); strict > = first max.
    float best = 0.0f;
    int   bi   = 0;

    while (mask) {
        const int m = __builtin_amdgcn_readfirstlane(__builtin_ctzll(mask));
        mask &= mask - 1;
        // GT m fragments pulled from lane m's registers (v_readlane -> SGPR)
        const float gx0 = readlane_f(gl.x, m);
        const float gy0 = readlane_f(gl.y, m);
        const float gx1 = readlane_f(gl.z, m);
        const float gy1 = readlane_f(gl.w, m);
        const float ab  = readlane_f(area_l, m);

        float ltx = fmaxf(ax0, gx0);
        float lty = fmaxf(ay0, gy0);
        float rbx = fminf(ax1, gx1);
        float rby = fminf(ay1, gy1);
        float w = fmaxf(rbx - ltx, 0.0f);
        float h = fmaxf(rby - lty, 0.0f);
        float inter = w * h;

        if (__any(inter > 0.0f)) {
            const float lbm = readlane_f(lbl, m);
            float iou = inter / ((area_a + ab) - inter);  // IEEE div: bit-exact vs np
            if (iou > best) { best = iou; bi = m; }
            // Column candidate: iou >= lb[m] (lb <= column max by construction,
            // so this catches the argmax and all earlier ties — rare in practice).
            if (valid && iou >= lbm) {
                unsigned long long p =
                    (((unsigned long long)__float_as_uint(iou)) << 32)
                    | (unsigned int)(~(unsigned int)n);
                atomicMax(&col[b * M + m], p);
            }
        }
    }

    if (valid) {
        float cv;
        if (best < BG_T)      cv = 0.0f;
        else if (best < FG_T) cv = -1.0f;
        else                  cv = (float)(lab[b * M + bi] + 1);

        float4 g = gtb[bi];   // divergent gather, tiny table, L1-resident
        float bcx = (g.x + g.z) / 2.0f;
        float bcy = (g.y + g.w) / 2.0f;
        float bw  = g.z - g.x;
        float bh  = g.w - g.y;
        float lx = ((bcx - d.x) / d.z) / 0.1f;
        float ly = ((bcy - d.y) / d.w) / 0.1f;
        float lw = __logf(bw / d.z) / 0.2f;   // ~1e-6 abs err vs 3.54 threshold
        float lh = __logf(bh / d.w) / 0.2f;

        ((float4*)out_loc)[(size_t)b * N + n] = make_float4(lx, ly, lw, lh);
        out_cls[(size_t)b * N + n] = cv;
    }
}

// Apply the best_p_idx override: best_t_idx[best_p[m]] = m (last write wins),
// best_t -> 2.0 so cls = lab+1 and loc re-encoded from gt[m].
__global__ void fixup_kernel(
    const float* __restrict__ gt,
    const int*   __restrict__ lab,
    const float* __restrict__ db,
    const unsigned long long* __restrict__ col,
    float* __restrict__ out_loc,
    float* __restrict__ out_cls,
    int N)
{
#pragma clang fp contract(off)
    __shared__ int s_a[M];
    const int b = blockIdx.x;
    const int m = threadIdx.x;  // 64 threads

    unsigned long long p = col[b * M + m];
    // p==0: no anchor overlapped GT m -> np argmax of all-zero column = 0.
    int a = (p == 0ull) ? 0 : (int)(~(unsigned int)(p & 0xFFFFFFFFull));
    s_a[m] = a;
    __syncthreads();

    // last-write-wins for duplicate anchors (np fancy assignment semantics)
    bool write = true;
    for (int mm = m + 1; mm < M; ++mm) {
        if (s_a[mm] == a) { write = false; break; }
    }
    if (write) {
        float4 d = ((const float4*)db)[a];
        float4 g = ((const float4*)gt)[b * M + m];
        float bcx = (g.x + g.z) / 2.0f;
        float bcy = (g.y + g.w) / 2.0f;
        float bw  = g.z - g.x;
        float bh  = g.w - g.y;
        float lx = ((bcx - d.x) / d.z) / 0.1f;
        float ly = ((bcy - d.y) / d.w) / 0.1f;
        float lw = __logf(bw / d.z) / 0.2f;
        float lh = __logf(bh / d.w) / 0.2f;

        ((float4*)out_loc)[(size_t)b * N + a] = make_float4(lx, ly, lw, lh);
        out_cls[(size_t)b * N + a] = (float)(lab[b * M + m] + 1);  // best_t = 2.0
    }
}

extern "C" void kernel_launch(void* const* d_in, const int* in_sizes, int n_in,
                              void* d_out, int out_size, void* d_ws, size_t ws_size,
                              hipStream_t stream) {
    const float* gt  = (const float*)d_in[0];   // gt_boxes  [B, M, 4] xyxy
    const int*   lab = (const int*)d_in[1];     // labels    [B, M]
    const float* db  = (const float*)d_in[2];   // default_boxes [N, 4] xywh

    const int B = in_sizes[1] / M;
    const int N = in_sizes[2] / 4;

    float* out_loc = (float*)d_out;                       // [B, N, 4]
    float* out_cls = out_loc + (size_t)B * N * 4;         // [B, N]

    unsigned long long* col = (unsigned long long*)d_ws;          // [B, M] u64
    float*              lbp = (float*)(col + (size_t)B * M);      // [B, M] f32

    lb_kernel<<<dim3(B), dim3(M), 0, stream>>>(gt, db, lbp, col);
    row_kernel<<<dim3((N + 255) / 256, B), dim3(256), 0, stream>>>(
        gt, lab, db, lbp, out_loc, out_cls, col, N);
    fixup_kernel<<<dim3(B), dim3(M), 0, stream>>>(gt, lab, db, col, out_loc, out_cls, N);
}